// Round 14
// baseline (49.604 us; speedup 1.0000x reference)
//
#include <hip/hip_runtime.h>

#define B_ 2
#define A_ 16384
#define C_ 15
#define G_ 16
#define D2Rf 0.017453292519943295f
#define ENC_HALF 0xBF000000u   // enc(0.5f)
#define ENC_04   0xBECCCCCDu   // enc(0.4f)
#define NB_ 256                // K1 blocks; 128 anchors each
#define NT_ 128                // K1 threads per block
#define OSTR 25                // LDS ord-array stride (gcd(25,32)=1)

__device__ __forceinline__ unsigned enc_f32(float f) {
    unsigned u = __float_as_uint(f);
    return u ^ ((u >> 31) ? 0xFFFFFFFFu : 0x80000000u);
}

// ---------------------------------------------------------------------------
// Rotated IoU (R12's verified fast clip: pseudo-angle key, pairwise rank,
// scatter-by-rank into per-thread LDS, sorted-walk shoelace).
// ---------------------------------------------------------------------------
__device__ __forceinline__ float pseudo_angle(float y, float x) {
    float d = fabsf(x) + fabsf(y);
    float r = y / d;
    float p = (x >= 0.f) ? r : ((y >= 0.f) ? 2.f - r : -2.f - r);
    return (d == 0.f) ? 0.f : p;
}

__device__ __forceinline__ void rect_corners5(const float* b, float X[4], float Y[4],
                                              float* cth, float* sth) {
    float th = b[4] * D2Rf;
    float c = cosf(th), s = sinf(th);
    *cth = c; *sth = s;
    const float SX[4] = {-1.f, 1.f, 1.f, -1.f};
    const float SY[4] = {-1.f, -1.f, 1.f, 1.f};
    float hw = 0.5f * b[2], hh = 0.5f * b[3];
#pragma unroll
    for (int i = 0; i < 4; ++i) {
        float dx = hw * SX[i];
        float dy = hh * SY[i];
        X[i] = b[0] + dx * c - dy * s;
        Y[i] = b[1] + dx * s + dy * c;
    }
}

__device__ __forceinline__ float rotated_iou_pair(const float* ab, const float* gb,
                                                  float* ox, float* oy) {
    float ax[4], ay[4], gx[4], gy[4];
    float cA, sA, cG, sG;
    rect_corners5(ab, ax, ay, &cA, &sA);
    rect_corners5(gb, gx, gy, &cG, &sG);

    float rx[24], ry[24];
    unsigned msk = 0u;

#pragma unroll
    for (int i = 0; i < 4; ++i) {
        float dx = ax[i] - gb[0], dy = ay[i] - gb[1];
        float lx = dx * cG + dy * sG;
        float ly = -dx * sG + dy * cG;
        bool in = (fabsf(lx) <= 0.5f * gb[2] + 1e-4f) && (fabsf(ly) <= 0.5f * gb[3] + 1e-4f);
        rx[i] = ax[i]; ry[i] = ay[i];
        if (in) msk |= (1u << i);
    }
#pragma unroll
    for (int i = 0; i < 4; ++i) {
        float dx = gx[i] - ab[0], dy = gy[i] - ab[1];
        float lx = dx * cA + dy * sA;
        float ly = -dx * sA + dy * cA;
        bool in = (fabsf(lx) <= 0.5f * ab[2] + 1e-4f) && (fabsf(ly) <= 0.5f * ab[3] + 1e-4f);
        rx[4 + i] = gx[i]; ry[4 + i] = gy[i];
        if (in) msk |= (1u << (4 + i));
    }
#pragma unroll
    for (int i = 0; i < 4; ++i) {
        float p0x = ax[i], p0y = ay[i];
        float p1x = ax[(i + 1) & 3], p1y = ay[(i + 1) & 3];
        float d1x = p1x - p0x, d1y = p1y - p0y;
#pragma unroll
        for (int j = 0; j < 4; ++j) {
            float q0x = gx[j], q0y = gy[j];
            float q1x = gx[(j + 1) & 3], q1y = gy[(j + 1) & 3];
            float d2x = q1x - q0x, d2y = q1y - q0y;
            float rrx = q0x - p0x, rry = q0y - p0y;
            float den = d1x * d2y - d1y * d2x;
            float safe = (fabsf(den) < 1e-8f) ? 1.f : den;
            float t = (rrx * d2y - rry * d2x) / safe;
            float u = (rrx * d1y - rry * d1x) / safe;
            bool ok = (fabsf(den) >= 1e-8f) && (t >= 0.f) && (t <= 1.f) && (u >= 0.f) && (u <= 1.f);
            int k = 8 + i * 4 + j;
            rx[k] = p0x + t * d1x;
            ry[k] = p0y + t * d1y;
            if (ok) msk |= (1u << k);
        }
    }

    int cnt = __popc(msk);
    float sx = 0.f, sy = 0.f;
#pragma unroll
    for (int k = 0; k < 24; ++k)
        if ((msk >> k) & 1u) { sx += rx[k]; sy += ry[k]; }
    float cnf = fmaxf((float)cnt, 1.f);
    float cenx = sx / cnf, ceny = sy / cnf;

    const unsigned long long UNM = ((unsigned long long)enc_f32(1e9f)) << 5;
    unsigned long long kk[24];
#pragma unroll
    for (int k = 0; k < 24; ++k) {
        if ((msk >> k) & 1u) {
            rx[k] -= cenx; ry[k] -= ceny;
            kk[k] = (((unsigned long long)enc_f32(pseudo_angle(ry[k], rx[k]))) << 5)
                    | (unsigned)k;
        } else {
            kk[k] = UNM | (unsigned)k;
        }
    }

    // pairwise rank: for each pair exactly one side increments
    int rnk[24];
#pragma unroll
    for (int k = 0; k < 24; ++k) rnk[k] = 0;
#pragma unroll
    for (int k = 1; k < 24; ++k) {
#pragma unroll
        for (int j = 0; j < k; ++j) {
            bool c = kk[j] < kk[k];
            rnk[k] += c ? 1 : 0;
            rnk[j] += c ? 0 : 1;
        }
    }

#pragma unroll
    for (int k = 0; k < 24; ++k) {
        if ((msk >> k) & 1u) { ox[rnk[k]] = rx[k]; oy[rnk[k]] = ry[k]; }
    }

    float inter = 0.f;
    if (cnt >= 3) {
        float x0 = ox[0], y0 = oy[0];
        float xp = x0, yp = y0, ssum = 0.f;
        for (int r = 1; r < cnt; ++r) {
            float xc = ox[r], yc = oy[r];
            ssum += xp * yc - yp * xc;
            xp = xc; yp = yc;
        }
        ssum += xp * y0 - yp * x0;
        inter = 0.5f * fabsf(ssum);
    }
    float uni = ab[2] * ab[3] + gb[2] * gb[3] - inter;
    return inter / fmaxf(uni, 1e-8f);
}

// focal sum over 15 classes for one anchor, target class cls (-1 = all zeros)
__device__ __forceinline__ float focal_row(const float* pr, int cls) {
    float s = 0.f;
#pragma unroll
    for (int c = 0; c < C_; ++c) {
        float tgt = (c == cls) ? 1.f : 0.f;
        float pv = fminf(fmaxf(pr[c], 1e-4f), 1.f - 1e-4f);
        float af = (tgt == 1.f) ? 0.25f : 0.75f;
        float x = (tgt == 1.f) ? (1.f - pv) : pv;
        float fw = af * x * x;
        float bce = -(tgt * logf(pv + 1e-6f) + (1.f - tgt) * logf(1.f - pv + 1e-6f));
        s += fw * bce;
    }
    return s;
}

__device__ __forceinline__ float sl1_row(const float* ex, const float* rp,
                                         const float* g6) {
    float ew = fmaxf(ex[2], 1.f), eh = fmaxf(ex[3], 1.f);
    float gw = fmaxf(g6[2], 1.f), gh = fmaxf(g6[3], 1.f);
    float tg[5];
    tg[0] = 10.f * (g6[0] - ex[0]) / ew;
    tg[1] = 10.f * (g6[1] - ex[1]) / eh;
    tg[2] = 10.f * logf(gw / ew);
    tg[3] = 5.f * logf(gh / eh);
    tg[4] = 15.f * (tanf(g6[4] * D2Rf) - tanf(ex[4] * D2Rf));
    const float BETAf = (float)(1.0 / 9.0);
    float s = 0.f;
#pragma unroll
    for (int i = 0; i < 5; ++i) {
        float d = fabsf(rp[i] - tg[i]);
        s += (d < BETAf) ? 0.5f * d * d / BETAf : d - 0.5f * BETAf;
    }
    return s;
}

// ---------------------------------------------------------------------------
// K1: gate + heavy + loss partials. 256 blocks x 128 threads; block owns 128
// anchors (1 thread = 1 anchor in gate and loss). Heavy pairs of an anchor
// live entirely in the owner block -> row max is LDS-local; anchors are
// uniform-random in this input -> ~102 items/block, ~1 clip/thread.
// Outputs (all fully rewritten every call -> deterministic, replay-safe):
// rowMaxArg (per anchor), partials (16 colmax cells/block), pcls/preg/pnp.
// pos here EXCLUDES forced-positives; K2 applies delta fixups.
// ---------------------------------------------------------------------------
__global__ void __launch_bounds__(NT_, 1)
fused_kernel(const float* __restrict__ cls_p,
             const float* __restrict__ reg_p,
             const float* __restrict__ anc,
             const float* __restrict__ ann,
             unsigned long long* __restrict__ rowMaxArg,   // B_*A_
             unsigned long long* __restrict__ partials,    // NB_*16
             float* __restrict__ pcls, float* __restrict__ preg,
             int* __restrict__ pnp) {
    __shared__ unsigned long long rowkey[NT_];
    __shared__ unsigned long long cells[16];
    __shared__ unsigned short list[NT_ * 16];
    __shared__ int ss[NT_];
    __shared__ float ordx[NT_ * OSTR];
    __shared__ float ordy[NT_ * OSTR];

    const int tid = threadIdx.x;
    const int blk = blockIdx.x;
    const int b = blk >> 7;                 // 128 blocks per image
    const int t = blk * NT_ + tid;          // global anchor id
    float* ox = ordx + tid * OSTR;
    float* oy = ordy + tid * OSTR;

    if (tid < 16) cells[tid] = 0ull;

    // ---- gate: 1 thread per anchor ----
    const float* ab = anc + (size_t)t * 5;
    float a0 = ab[0], a1 = ab[1], a2 = ab[2], a3 = ab[3];
    float sa = 0.5f * fmaxf(a2, a3);

    unsigned passmask = 0u;
    unsigned long long rk = 0ull;
#pragma unroll
    for (int g = 0; g < G_; ++g) {
        const float* gb = ann + ((size_t)b * G_ + g) * 6;   // 96 B, L1-resident
        float v;
        if (gb[5] == -1.0f) {
            v = -1.0f;
        } else {
            float sb = 0.5f * fmaxf(gb[2], gb[3]);
            float iw = fminf(a0 + sa, gb[0] + sb) - fmaxf(a0 - sa, gb[0] - sb);
            iw = fmaxf(iw, 0.f);
            float ih = fminf(a1 + sa, gb[1] + sb) - fmaxf(a1 - sa, gb[1] - sb);
            ih = fmaxf(ih, 0.f);
            float inter = iw * ih;
            float uni = 4.f * sa * sa + 4.f * sb * sb - inter;
            float ind = inter / fmaxf(uni, 1e-8f);
            if (ind > 0.1f) passmask |= (1u << g);
            v = 0.f;   // placeholder <= any heavy IoU, same tiebreak bits
        }
        unsigned long long key =
            ((unsigned long long)enc_f32(v) << 32) | (unsigned)(G_ - 1 - g);
        if (key > rk) rk = key;
    }
    rowkey[tid] = rk;

    // block scan -> compact LDS worklist
    int cnt = __popc(passmask);
    ss[tid] = cnt;
    __syncthreads();
    for (int s = 1; s < NT_; s <<= 1) {
        int v = (tid >= s) ? ss[tid - s] : 0;
        __syncthreads();
        ss[tid] += v;
        __syncthreads();
    }
    unsigned p = (unsigned)(ss[tid] - cnt);
#pragma unroll
    for (int g = 0; g < G_; ++g) {
        if ((passmask >> g) & 1u)
            list[p++] = (unsigned short)(((unsigned)tid << 4) | (unsigned)g);
    }
    __syncthreads();
    const unsigned n = (unsigned)ss[NT_ - 1];

    // ---- heavy: block-balanced (~102 items avg -> ~1 pass) ----
    for (unsigned i = (unsigned)tid; i < n; i += NT_) {
        unsigned e = (unsigned)list[i];
        int la = (int)(e >> 4), g = (int)(e & 15u);
        int t2 = blk * NT_ + la;
        float v = rotated_iou_pair(anc + (size_t)t2 * 5,
                                   ann + ((size_t)b * G_ + g) * 6, ox, oy);
        unsigned long long ev = (unsigned long long)enc_f32(v);
        atomicMax(&rowkey[la], (ev << 32) | (unsigned)(G_ - 1 - g));   // LDS
        unsigned aIdx = (unsigned)(t2 & (A_ - 1));
        atomicMax(&cells[g], (ev << 32) | (0xFFFFFFFFu - aIdx));      // LDS
    }
    __syncthreads();

    // ---- loss: 1 thread per anchor (pos WITHOUT forced; K2 fixes up) ----
    unsigned long long rkf = rowkey[tid];
    rowMaxArg[t] = rkf;                      // for K2 fixups
    unsigned ehi = (unsigned)(rkf >> 32);
    int arg = (G_ - 1) - (int)(rkf & 0xFu);
    bool pos = (ehi >= ENC_HALF);

    float csum = 0.f, rsum = 0.f;
    int posi = pos ? 1 : 0;
    const float* g6 = ann + ((size_t)b * G_ + arg) * 6;
    if (pos || ehi < ENC_04)
        csum = focal_row(cls_p + (size_t)t * C_, pos ? (int)g6[5] : -1);
    if (pos)
        rsum = sl1_row(ab, reg_p + (size_t)t * 5, g6);

    // block tree reduce (reuse ordx/ss as scratch)
    float* sc = ordx;            // 128 floats
    float* sr = ordx + NT_;      // 128 floats
    sc[tid] = csum; sr[tid] = rsum; ss[tid] = posi;
    __syncthreads();
    for (int s = NT_ / 2; s > 0; s >>= 1) {
        if (tid < s) {
            sc[tid] += sc[tid + s];
            sr[tid] += sr[tid + s];
            ss[tid] += ss[tid + s];
        }
        __syncthreads();
    }
    if (tid == 0) { pcls[blk] = sc[0]; preg[blk] = sr[0]; pnp[blk] = ss[0]; }
    if (tid < 16) partials[(size_t)blk * 16 + tid] = cells[tid];
}

// ---------------------------------------------------------------------------
// K2: finalize. ONE block x 256 threads, no atomics, fully deterministic.
// colmax reduce (default candidate (0.0, anchor 0): all non-heavy entries of
// a valid gt column are exactly 0.0) -> <=32 forced-positive delta fixups
// (recompute that anchor's focal/SL1 old-vs-new) -> per-image ordered sums
// -> out[2].
// ---------------------------------------------------------------------------
__global__ void __launch_bounds__(256, 1)
final_kernel(const float* __restrict__ cls_p,
             const float* __restrict__ reg_p,
             const float* __restrict__ anc,
             const float* __restrict__ ann,
             const unsigned long long* __restrict__ rowMaxArg,
             const unsigned long long* __restrict__ partials,
             const float* __restrict__ pcls,
             const float* __restrict__ preg,
             const int* __restrict__ pnp,
             float* __restrict__ out) {
    __shared__ unsigned long long cred[256];
    __shared__ unsigned long long pk32[32];
    __shared__ float sc[128], sr[128];
    __shared__ int si[128];
    __shared__ float csB[B_], rsB[B_];
    __shared__ int npB[B_];
    __shared__ float fdc[32], fdr[32];
    __shared__ int fdn[32];
    __shared__ unsigned fA[32];

    const int tid = threadIdx.x;

    // ---- colmax: cell (b3,g3), 8 threads each over its image's 128 blocks --
    {
        int cc = tid >> 3, sub = tid & 7;
        int b3 = cc >> 4, g3 = cc & 15;
        unsigned long long m = 0ull;
        for (int k = sub; k < 128; k += 8)
            m = max(m, partials[(size_t)(b3 * 128 + k) * 16 + g3]);
        cred[tid] = m;
    }
    __syncthreads();
    if (tid < 32) {
        unsigned long long mm =
            ((unsigned long long)enc_f32(0.0f) << 32) | 0xFFFFFFFFu;  // (0.0, a=0)
        for (int j = 0; j < 8; ++j) mm = max(mm, cred[tid * 8 + j]);
        pk32[tid] = mm;
    }
    __syncthreads();

    // ---- per-image block-sum reduce (fixed tree -> deterministic) ----
    for (int bb = 0; bb < B_; ++bb) {
        if (tid < 128) {
            sc[tid] = pcls[bb * 128 + tid];
            sr[tid] = preg[bb * 128 + tid];
            si[tid] = pnp[bb * 128 + tid];
        }
        __syncthreads();
        for (int s = 64; s > 0; s >>= 1) {
            if (tid < s) {
                sc[tid] += sc[tid + s];
                sr[tid] += sr[tid + s];
                si[tid] += si[tid + s];
            }
            __syncthreads();
        }
        if (tid == 0) { csB[bb] = sc[0]; rsB[bb] = sr[0]; npB[bb] = si[0]; }
        __syncthreads();
    }

    // ---- forced-positive fixups (<=32 candidate gts) ----
    if (tid < 32) {
        fdc[tid] = 0.f; fdr[tid] = 0.f; fdn[tid] = 0;
        int b2 = tid >> 4, g2 = tid & 15;
        unsigned long long pk = pk32[tid];
        float lab = ann[((size_t)b2 * G_ + g2) * 6 + 5];
        unsigned hi = (unsigned)(pk >> 32);
        unsigned aidx = 0xFFFFFFFFu - (unsigned)pk;
        fA[tid] = (lab != -1.0f && hi < ENC_HALF) ? aidx : 0xFFFFFFFFu;
    }
    __syncthreads();
    if (tid < 32 && fA[tid] != 0xFFFFFFFFu) {
        int b2 = tid >> 4;
        bool dup = false;
        for (int j = b2 * 16; j < tid; ++j)
            if (fA[j] == fA[tid]) dup = true;          // anchor already forced
        if (!dup) {
            int aG = b2 * A_ + (int)fA[tid];
            unsigned long long rk2 = rowMaxArg[aG];
            unsigned eh2 = (unsigned)(rk2 >> 32);
            if (eh2 < ENC_HALF) {                      // not already positive
                int arg2 = (G_ - 1) - (int)(rk2 & 0xFu);
                const float* g62 = ann + ((size_t)b2 * G_ + arg2) * 6;
                const float* pr = cls_p + (size_t)aG * C_;
                float cnew = focal_row(pr, (int)g62[5]);
                float cold = (eh2 < ENC_04) ? focal_row(pr, -1) : 0.f;
                fdc[tid] = cnew - cold;
                fdr[tid] = sl1_row(anc + (size_t)aG * 5, reg_p + (size_t)aG * 5, g62);
                fdn[tid] = 1;
            }
        }
    }
    __syncthreads();

    if (tid == 0) {
        float cm = 0.f, rm = 0.f;
        for (int bb = 0; bb < B_; ++bb) {
            float cs = csB[bb], rs = rsB[bb];
            int np = npB[bb];
            for (int g = 0; g < 16; ++g) {             // fixed order
                cs += fdc[bb * 16 + g];
                rs += fdr[bb * 16 + g];
                np += fdn[bb * 16 + g];
            }
            bool has = false;
            for (int g = 0; g < G_; ++g)
                if (ann[((size_t)bb * G_ + g) * 6 + 5] != -1.0f) has = true;
            float c_ = cs / fmaxf((float)np, 1.f);
            int d5 = np * 5; if (d5 < 1) d5 = 1;
            float r_ = (np > 0) ? rs / (float)d5 : 0.f;
            cm += has ? c_ : 0.f;
            rm += has ? r_ : 0.f;
        }
        out[0] = cm / (float)B_;
        out[1] = rm / (float)B_;
    }
}

// ---------------------------------------------------------------------------
extern "C" void kernel_launch(void* const* d_in, const int* in_sizes, int n_in,
                              void* d_out, int out_size, void* d_ws, size_t ws_size,
                              hipStream_t stream) {
    const float* cls_p = (const float*)d_in[0];   // (B,A,C)
    const float* reg_p = (const float*)d_in[1];   // (B,A,5)
    const float* anc   = (const float*)d_in[2];   // (B,A,5)
    const float* ann   = (const float*)d_in[3];   // (B,G,6)
    float* out = (float*)d_out;

    // workspace: every word consumed is rewritten by K1 each call ->
    // deterministic under graph replay; no counters, no memset, no atomics.
    char* ws = (char*)d_ws;
    unsigned long long* rowMaxArg = (unsigned long long*)ws;          // 256 KB
    unsigned long long* partials = rowMaxArg + (size_t)B_ * A_;       // NB_*16*8 = 32 KB
    float* pcls = (float*)(partials + (size_t)NB_ * 16);              // NB_
    float* preg = pcls + NB_;
    int*   pnp  = (int*)(preg + NB_);

    fused_kernel<<<NB_, NT_, 0, stream>>>(cls_p, reg_p, anc, ann,
                                          rowMaxArg, partials, pcls, preg, pnp);
    final_kernel<<<1, 256, 0, stream>>>(cls_p, reg_p, anc, ann, rowMaxArg,
                                        partials, pcls, preg, pnp, out);
}

// Round 15
// 39.574 us; speedup vs baseline: 1.2534x; 1.2534x over previous
//
#include <hip/hip_runtime.h>

#define B_ 2
#define A_ 16384
#define C_ 15
#define G_ 16
#define D2Rf 0.017453292519943295f
#define ENC_HALF 0xBF000000u   // enc(0.5f)
#define ENC_04   0xBECCCCCDu   // enc(0.4f)
#define K1B 256                // K1 blocks; 128 anchors each
#define K1T 256                // K1 threads (2x anchors -> 1-pass heavy)
#define LB_ 128                // K2 blocks
#define OSTR 25                // LDS ord-array stride (gcd(25,32)=1)

__device__ __forceinline__ unsigned enc_f32(float f) {
    unsigned u = __float_as_uint(f);
    return u ^ ((u >> 31) ? 0xFFFFFFFFu : 0x80000000u);
}

// ---------------------------------------------------------------------------
// Rotated IoU (R12's verified fast clip: pseudo-angle key, pairwise rank,
// scatter-by-rank into per-thread LDS, sorted-walk shoelace). absmax 0.0.
// ---------------------------------------------------------------------------
__device__ __forceinline__ float pseudo_angle(float y, float x) {
    float d = fabsf(x) + fabsf(y);
    float r = y / d;
    float p = (x >= 0.f) ? r : ((y >= 0.f) ? 2.f - r : -2.f - r);
    return (d == 0.f) ? 0.f : p;
}

__device__ __forceinline__ void rect_corners5(const float* b, float X[4], float Y[4],
                                              float* cth, float* sth) {
    float th = b[4] * D2Rf;
    float c = cosf(th), s = sinf(th);
    *cth = c; *sth = s;
    const float SX[4] = {-1.f, 1.f, 1.f, -1.f};
    const float SY[4] = {-1.f, -1.f, 1.f, 1.f};
    float hw = 0.5f * b[2], hh = 0.5f * b[3];
#pragma unroll
    for (int i = 0; i < 4; ++i) {
        float dx = hw * SX[i];
        float dy = hh * SY[i];
        X[i] = b[0] + dx * c - dy * s;
        Y[i] = b[1] + dx * s + dy * c;
    }
}

__device__ __forceinline__ float rotated_iou_pair(const float* ab, const float* gb,
                                                  float* ox, float* oy) {
    float ax[4], ay[4], gx[4], gy[4];
    float cA, sA, cG, sG;
    rect_corners5(ab, ax, ay, &cA, &sA);
    rect_corners5(gb, gx, gy, &cG, &sG);

    float rx[24], ry[24];
    unsigned msk = 0u;

#pragma unroll
    for (int i = 0; i < 4; ++i) {
        float dx = ax[i] - gb[0], dy = ay[i] - gb[1];
        float lx = dx * cG + dy * sG;
        float ly = -dx * sG + dy * cG;
        bool in = (fabsf(lx) <= 0.5f * gb[2] + 1e-4f) && (fabsf(ly) <= 0.5f * gb[3] + 1e-4f);
        rx[i] = ax[i]; ry[i] = ay[i];
        if (in) msk |= (1u << i);
    }
#pragma unroll
    for (int i = 0; i < 4; ++i) {
        float dx = gx[i] - ab[0], dy = gy[i] - ab[1];
        float lx = dx * cA + dy * sA;
        float ly = -dx * sA + dy * cA;
        bool in = (fabsf(lx) <= 0.5f * ab[2] + 1e-4f) && (fabsf(ly) <= 0.5f * ab[3] + 1e-4f);
        rx[4 + i] = gx[i]; ry[4 + i] = gy[i];
        if (in) msk |= (1u << (4 + i));
    }
#pragma unroll
    for (int i = 0; i < 4; ++i) {
        float p0x = ax[i], p0y = ay[i];
        float p1x = ax[(i + 1) & 3], p1y = ay[(i + 1) & 3];
        float d1x = p1x - p0x, d1y = p1y - p0y;
#pragma unroll
        for (int j = 0; j < 4; ++j) {
            float q0x = gx[j], q0y = gy[j];
            float q1x = gx[(j + 1) & 3], q1y = gy[(j + 1) & 3];
            float d2x = q1x - q0x, d2y = q1y - q0y;
            float rrx = q0x - p0x, rry = q0y - p0y;
            float den = d1x * d2y - d1y * d2x;
            float safe = (fabsf(den) < 1e-8f) ? 1.f : den;
            float t = (rrx * d2y - rry * d2x) / safe;
            float u = (rrx * d1y - rry * d1x) / safe;
            bool ok = (fabsf(den) >= 1e-8f) && (t >= 0.f) && (t <= 1.f) && (u >= 0.f) && (u <= 1.f);
            int k = 8 + i * 4 + j;
            rx[k] = p0x + t * d1x;
            ry[k] = p0y + t * d1y;
            if (ok) msk |= (1u << k);
        }
    }

    int cnt = __popc(msk);
    float sx = 0.f, sy = 0.f;
#pragma unroll
    for (int k = 0; k < 24; ++k)
        if ((msk >> k) & 1u) { sx += rx[k]; sy += ry[k]; }
    float cnf = fmaxf((float)cnt, 1.f);
    float cenx = sx / cnf, ceny = sy / cnf;

    const unsigned long long UNM = ((unsigned long long)enc_f32(1e9f)) << 5;
    unsigned long long kk[24];
#pragma unroll
    for (int k = 0; k < 24; ++k) {
        if ((msk >> k) & 1u) {
            rx[k] -= cenx; ry[k] -= ceny;
            kk[k] = (((unsigned long long)enc_f32(pseudo_angle(ry[k], rx[k]))) << 5)
                    | (unsigned)k;
        } else {
            kk[k] = UNM | (unsigned)k;
        }
    }

    // pairwise rank: for each pair exactly one side increments
    int rnk[24];
#pragma unroll
    for (int k = 0; k < 24; ++k) rnk[k] = 0;
#pragma unroll
    for (int k = 1; k < 24; ++k) {
#pragma unroll
        for (int j = 0; j < k; ++j) {
            bool c = kk[j] < kk[k];
            rnk[k] += c ? 1 : 0;
            rnk[j] += c ? 0 : 1;
        }
    }

#pragma unroll
    for (int k = 0; k < 24; ++k) {
        if ((msk >> k) & 1u) { ox[rnk[k]] = rx[k]; oy[rnk[k]] = ry[k]; }
    }

    float inter = 0.f;
    if (cnt >= 3) {
        float x0 = ox[0], y0 = oy[0];
        float xp = x0, yp = y0, ssum = 0.f;
        for (int r = 1; r < cnt; ++r) {
            float xc = ox[r], yc = oy[r];
            ssum += xp * yc - yp * xc;
            xp = xc; yp = yc;
        }
        ssum += xp * y0 - yp * x0;
        inter = 0.5f * fabsf(ssum);
    }
    float uni = ab[2] * ab[3] + gb[2] * gb[3] - inter;
    return inter / fmaxf(uni, 1e-8f);
}

// ---------------------------------------------------------------------------
// K1: gate + block-local heavy. 256 blocks x 256 threads; block owns 128
// anchors. Gate on threads 0-127 (one anchor each); ~102 heavy items spread
// over 256 threads -> guaranteed ~1 clip pass (same critical path as a
// globally balanced list, minus the worklist L2 round-trip + binary search).
// Outputs fully rewritten each call: rowMaxArg (complete per anchor, light
// placeholder max'd with block-local heavy keys), partials (16 colmax cells
// per block), ctr[0]=0 (K2's arrival counter).
// ---------------------------------------------------------------------------
__global__ void __launch_bounds__(K1T, 1)
gate_heavy_kernel(const float* __restrict__ anc,
                  const float* __restrict__ ann,
                  unsigned long long* __restrict__ rowMaxArg,   // B_*A_
                  unsigned long long* __restrict__ partials,    // K1B*16
                  unsigned* __restrict__ ctr) {
    __shared__ unsigned long long rowkey[128];
    __shared__ unsigned long long cells[16];
    __shared__ unsigned short list[2048];
    __shared__ int ss[128];
    __shared__ float ordx[K1T * OSTR];
    __shared__ float ordy[K1T * OSTR];

    const int tid = threadIdx.x;
    const int blk = blockIdx.x;
    const int b = blk >> 7;                 // 128 blocks per image
    float* ox = ordx + tid * OSTR;
    float* oy = ordy + tid * OSTR;

    if (blk == 0 && tid == 0) ctr[0] = 0u;  // K2 arrival counter
    if (tid < 16) cells[tid] = 0ull;

    // ---- gate: threads 0-127, one anchor each ----
    unsigned passmask = 0u;
    if (tid < 128) {
        const int t = blk * 128 + tid;
        const float* ab = anc + (size_t)t * 5;
        float a0 = ab[0], a1 = ab[1];
        float sa = 0.5f * fmaxf(ab[2], ab[3]);
        unsigned long long rk = 0ull;
#pragma unroll
        for (int g = 0; g < G_; ++g) {
            const float* gb = ann + ((size_t)b * G_ + g) * 6;   // L1-resident
            float v;
            if (gb[5] == -1.0f) {
                v = -1.0f;
            } else {
                float sb = 0.5f * fmaxf(gb[2], gb[3]);
                float iw = fminf(a0 + sa, gb[0] + sb) - fmaxf(a0 - sa, gb[0] - sb);
                iw = fmaxf(iw, 0.f);
                float ih = fminf(a1 + sa, gb[1] + sb) - fmaxf(a1 - sa, gb[1] - sb);
                ih = fmaxf(ih, 0.f);
                float inter = iw * ih;
                float uni = 4.f * sa * sa + 4.f * sb * sb - inter;
                float ind = inter / fmaxf(uni, 1e-8f);
                if (ind > 0.1f) passmask |= (1u << g);
                v = 0.f;   // placeholder <= any heavy IoU, same tiebreak bits
            }
            unsigned long long key =
                ((unsigned long long)enc_f32(v) << 32) | (unsigned)(G_ - 1 - g);
            if (key > rk) rk = key;
        }
        rowkey[tid] = rk;
        ss[tid] = __popc(passmask);
    }
    __syncthreads();

    // scan over the 128 anchor counts -> compact LDS worklist
    for (int s = 1; s < 128; s <<= 1) {
        int v = (tid < 128 && tid >= s) ? ss[tid - s] : 0;
        __syncthreads();
        if (tid < 128) ss[tid] += v;
        __syncthreads();
    }
    if (tid < 128) {
        unsigned p = (unsigned)(ss[tid] - __popc(passmask));
#pragma unroll
        for (int g = 0; g < G_; ++g) {
            if ((passmask >> g) & 1u)
                list[p++] = (unsigned short)(((unsigned)tid << 4) | (unsigned)g);
        }
    }
    __syncthreads();
    const unsigned n = (unsigned)ss[127];

    // ---- heavy: ~102 items over 256 threads -> 1 pass ----
    for (unsigned i = (unsigned)tid; i < n; i += K1T) {
        unsigned e = (unsigned)list[i];
        int la = (int)(e >> 4), g = (int)(e & 15u);
        int t2 = blk * 128 + la;
        float v = rotated_iou_pair(anc + (size_t)t2 * 5,
                                   ann + ((size_t)b * G_ + g) * 6, ox, oy);
        unsigned long long ev = (unsigned long long)enc_f32(v);
        atomicMax(&rowkey[la], (ev << 32) | (unsigned)(G_ - 1 - g));   // LDS
        unsigned aIdx = (unsigned)(t2 & (A_ - 1));
        atomicMax(&cells[g], (ev << 32) | (0xFFFFFFFFu - aIdx));      // LDS
    }
    __syncthreads();

    if (tid < 128) rowMaxArg[blk * 128 + tid] = rowkey[tid];
    if (tid < 16) partials[(size_t)blk * 16 + tid] = cells[tid];
}

// ---------------------------------------------------------------------------
// K2: colfinal + loss + final (R12's loss kernel; colfinal adapted to the
// image-partitioned K1B x 16 partials). 128 blocks x 256 thr. Last-arriving
// block does the deterministic ordered final combine (ctr zeroed by K1).
// ---------------------------------------------------------------------------
__global__ void __launch_bounds__(256, 1)
loss_kernel(const float* __restrict__ cls_p,
            const float* __restrict__ reg_p,
            const float* __restrict__ anc,
            const float* __restrict__ ann,
            const unsigned long long* __restrict__ rowMaxArg,
            const unsigned long long* __restrict__ partials,
            float* __restrict__ pcls,
            float* __restrict__ preg,
            int* __restrict__ pnp,
            unsigned* __restrict__ ctr,
            float* __restrict__ out) {
    __shared__ unsigned long long red[256];
    __shared__ unsigned long long pk32[32];
    __shared__ float sc[256], sr[256];
    __shared__ int sp[256];
    __shared__ int lastFlag;

    const int tid = threadIdx.x;

    // ---- colfinal: cell (b3,g3) reduced by 8 threads over image b3's 128
    // blocks. Default candidate (0.0, anchor 0): every non-heavy entry of a
    // valid gt column is exactly 0.0 and anchor 0 is the smallest index.
    {
        int cc = tid >> 3, sub = tid & 7;
        int b3 = cc >> 4, g3 = cc & 15;
        unsigned long long m = 0ull;
        for (int k = sub; k < 128; k += 8)
            m = max(m, partials[(size_t)(b3 * 128 + k) * 16 + g3]);
        red[tid] = m;
    }
    __syncthreads();
    if (tid < 32) {
        unsigned long long mm =
            ((unsigned long long)enc_f32(0.0f) << 32) | 0xFFFFFFFFu;  // (0.0, a=0)
        for (int j = 0; j < 8; ++j) mm = max(mm, red[tid * 8 + j]);
        pk32[tid] = mm;
    }
    __syncthreads();

    // ---- per-anchor loss ----
    const int t = blockIdx.x * 256 + tid;
    const int b = t >> 14;
    const int a = t & (A_ - 1);

    unsigned long long rk = rowMaxArg[t];
    unsigned ehi = (unsigned)(rk >> 32);
    int arg = (G_ - 1) - (int)(rk & 0xFu);

    bool forcedf = false;
#pragma unroll
    for (int g = 0; g < G_; ++g) {
        unsigned long long pkv = pk32[b * G_ + g];
        float lab = ann[((size_t)b * G_ + g) * 6 + 5];
        unsigned hi = (unsigned)(pkv >> 32);
        unsigned ai = 0xFFFFFFFFu - (unsigned)pkv;
        forcedf |= (lab != -1.0f) && (hi < ENC_HALF) && (ai == (unsigned)a);
    }

    bool pos = (ehi >= ENC_HALF) || forcedf;
    const float* g6 = ann + ((size_t)b * G_ + arg) * 6;
    int cls = (int)g6[5];

    float csum = 0.f;
    if (pos || ehi < ENC_04) {
        const float* pr = cls_p + (size_t)t * C_;
#pragma unroll
        for (int c = 0; c < C_; ++c) {
            float tgt = (pos && c == cls) ? 1.f : 0.f;
            float pv = fminf(fmaxf(pr[c], 1e-4f), 1.f - 1e-4f);
            float af = (tgt == 1.f) ? 0.25f : 0.75f;
            float x = (tgt == 1.f) ? (1.f - pv) : pv;
            float fw = af * x * x;
            float bce = -(tgt * logf(pv + 1e-6f) + (1.f - tgt) * logf(1.f - pv + 1e-6f));
            csum += fw * bce;
        }
    }

    float rsum = 0.f;
    if (pos) {
        const float* ex = anc + (size_t)t * 5;
        const float* rp = reg_p + (size_t)t * 5;
        float ew = fmaxf(ex[2], 1.f), eh2 = fmaxf(ex[3], 1.f);
        float gw = fmaxf(g6[2], 1.f), gh = fmaxf(g6[3], 1.f);
        float tg[5];
        tg[0] = 10.f * (g6[0] - ex[0]) / ew;
        tg[1] = 10.f * (g6[1] - ex[1]) / eh2;
        tg[2] = 10.f * logf(gw / ew);
        tg[3] = 5.f * logf(gh / eh2);
        tg[4] = 15.f * (tanf(g6[4] * D2Rf) - tanf(ex[4] * D2Rf));
        const float BETAf = (float)(1.0 / 9.0);
#pragma unroll
        for (int i = 0; i < 5; ++i) {
            float d = fabsf(rp[i] - tg[i]);
            rsum += (d < BETAf) ? 0.5f * d * d / BETAf : d - 0.5f * BETAf;
        }
    }

    sc[tid] = csum; sr[tid] = rsum; sp[tid] = pos ? 1 : 0;
    __syncthreads();
    for (int s = 128; s > 0; s >>= 1) {
        if (tid < s) {
            sc[tid] += sc[tid + s];
            sr[tid] += sr[tid + s];
            sp[tid] += sp[tid + s];
        }
        __syncthreads();
    }
    if (tid == 0) {
        pcls[blockIdx.x] = sc[0];
        preg[blockIdx.x] = sr[0];
        pnp[blockIdx.x] = sp[0];
        __threadfence();   // release partials
        unsigned v = atomicAdd(ctr, 1u);   // single RMW, no spinning
        lastFlag = (v == (unsigned)(LB_ - 1));
    }
    __syncthreads();

    // ---- last-arriving block: deterministic ordered final combine ----
    if (lastFlag) {
        __threadfence();   // acquire
        if (tid < LB_) {
            sc[tid] = pcls[tid];
            sr[tid] = preg[tid];
            sp[tid] = pnp[tid];
        }
        __syncthreads();
        if (tid == 0) {
            const int BPI = LB_ / B_;   // 64 blocks per image
            float cm = 0.f, rm = 0.f;
            for (int bb = 0; bb < B_; ++bb) {
                float cs = 0.f, rs = 0.f; int np = 0;
                for (int i = 0; i < BPI; ++i) {
                    cs += sc[bb * BPI + i];
                    rs += sr[bb * BPI + i];
                    np += sp[bb * BPI + i];
                }
                bool has = false;
                for (int g = 0; g < G_; ++g)
                    if (ann[((size_t)bb * G_ + g) * 6 + 5] != -1.0f) has = true;
                float c_ = cs / fmaxf((float)np, 1.f);
                int d5 = np * 5; if (d5 < 1) d5 = 1;
                float r_ = (np > 0) ? rs / (float)d5 : 0.f;
                cm += has ? c_ : 0.f;
                rm += has ? r_ : 0.f;
            }
            out[0] = cm / (float)B_;
            out[1] = rm / (float)B_;
        }
    }
}

// ---------------------------------------------------------------------------
extern "C" void kernel_launch(void* const* d_in, const int* in_sizes, int n_in,
                              void* d_out, int out_size, void* d_ws, size_t ws_size,
                              hipStream_t stream) {
    const float* cls_p = (const float*)d_in[0];   // (B,A,C)
    const float* reg_p = (const float*)d_in[1];   // (B,A,5)
    const float* anc   = (const float*)d_in[2];   // (B,A,5)
    const float* ann   = (const float*)d_in[3];   // (B,G,6)
    float* out = (float*)d_out;

    // workspace: every word consumed is rewritten each call (ctr zeroed by
    // K1 block 0 before K2 runs -> deterministic, replay-safe; R12 pattern).
    char* ws = (char*)d_ws;
    unsigned* ctrp = (unsigned*)ws;                                   // 256 B
    unsigned long long* rowMaxArg = (unsigned long long*)(ws + 256);  // 256 KB
    unsigned long long* partials = rowMaxArg + (size_t)B_ * A_;       // K1B*16*8 = 32 KB
    float* pcls = (float*)(partials + (size_t)K1B * 16);              // LB_
    float* preg = pcls + LB_;
    int*   pnp  = (int*)(preg + LB_);

    gate_heavy_kernel<<<K1B, K1T, 0, stream>>>(anc, ann, rowMaxArg, partials, ctrp);
    loss_kernel<<<LB_, 256, 0, stream>>>(cls_p, reg_p, anc, ann, rowMaxArg,
                                         partials, pcls, preg, pnp, ctrp, out);
}

// Round 16
// 32.072 us; speedup vs baseline: 1.5466x; 1.2339x over previous
//
#include <hip/hip_runtime.h>

#define B_ 2
#define A_ 16384
#define C_ 15
#define G_ 16
#define D2Rf 0.017453292519943295f
#define ENC_HALF 0xBF000000u   // enc(0.5f)
#define ENC_04   0xBECCCCCDu   // enc(0.4f)
#define NSEG 128               // gate blocks / segments
#define HB_ 256                // heavy blocks
#define HT_ 128                // heavy threads per block
#define LB_ 128                // loss blocks
#define SEGCAP 4096            // per-segment worklist capacity (256*16 max)
#define PSTR 9                 // LDS polygon-buffer stride (2-way bank alias = free)

__device__ __forceinline__ unsigned enc_f32(float f) {
    unsigned u = __float_as_uint(f);
    return u ^ ((u >> 31) ? 0xFFFFFFFFu : 0x80000000u);
}

// ---------------------------------------------------------------------------
// Rotated IoU via Sutherland-Hodgman: clip rect A (CCW corners) against rect
// G's 4 half-planes. Output vertices emerge in boundary order -> shoelace
// directly; no angles, no sort, no centroid. Exact same polygon as the
// reference's enumerate+argsort construction (convex∩convex), fp rounding
// differs at ~1e-6 relative -- decision flips need a pair within that of a
// threshold and even then move the loss by ~0.01 << the 16.32 threshold.
// Polygon buffers are per-thread LDS slices (runtime-indexed appends).
// ---------------------------------------------------------------------------
__device__ __forceinline__ void rect_corners4(const float* b, float X[4], float Y[4]) {
    float th = b[4] * D2Rf;
    float c = cosf(th), s = sinf(th);
    const float SX[4] = {-1.f, 1.f, 1.f, -1.f};
    const float SY[4] = {-1.f, -1.f, 1.f, 1.f};
    float hw = 0.5f * b[2], hh = 0.5f * b[3];
#pragma unroll
    for (int i = 0; i < 4; ++i) {
        float dx = hw * SX[i];
        float dy = hh * SY[i];
        X[i] = b[0] + dx * c - dy * s;
        Y[i] = b[1] + dx * s + dy * c;
    }
}

__device__ __forceinline__ float rotated_iou_pair(const float* ab, const float* gb,
                                                  float* PX, float* PY,
                                                  float* QX, float* QY) {
    float ax[4], ay[4], gx[4], gy[4];
    rect_corners4(ab, ax, ay);
    rect_corners4(gb, gx, gy);

#pragma unroll
    for (int i = 0; i < 4; ++i) { PX[i] = ax[i]; PY[i] = ay[i]; }
    int n = 4;

    float* px = PX; float* py = PY;
    float* qx = QX; float* qy = QY;

#pragma unroll
    for (int j = 0; j < 4; ++j) {
        float e0x = gx[j], e0y = gy[j];
        float ex = gx[(j + 1) & 3] - e0x;
        float ey = gy[(j + 1) & 3] - e0y;
        int m = 0;
        float sxv = px[n - 1], syv = py[n - 1];
        float ss = ex * (syv - e0y) - ey * (sxv - e0x);   // >=0 = inside (CCW)
        for (int i = 0; i < n; ++i) {
            float exv = px[i], eyv = py[i];
            float se = ex * (eyv - e0y) - ey * (exv - e0x);
            if ((ss >= 0.f) != (se >= 0.f)) {
                float tpar = ss / (ss - se);
                qx[m] = sxv + tpar * (exv - sxv);
                qy[m] = syv + tpar * (eyv - syv);
                ++m;
            }
            if (se >= 0.f) { qx[m] = exv; qy[m] = eyv; ++m; }
            sxv = exv; syv = eyv; ss = se;
        }
        n = m;
        // swap P <-> Q
        float* tx = px; px = qx; qx = tx;
        float* ty = py; py = qy; qy = ty;
        if (n == 0) break;
    }

    float inter = 0.f;
    if (n >= 3) {
        float x0 = px[0], y0 = py[0];
        float xp = x0, yp = y0, ssum = 0.f;
        for (int r = 1; r < n; ++r) {
            float xc = px[r], yc = py[r];
            ssum += xp * yc - yp * xc;
            xp = xc; yp = yc;
        }
        ssum += xp * y0 - yp * x0;
        inter = 0.5f * fabsf(ssum);
    }
    float uni = ab[2] * ab[3] + gb[2] * gb[3] - inter;
    return inter / fmaxf(uni, 1e-8f);
}

// ---------------------------------------------------------------------------
// K1: gate. 128 blocks x 256 thr. Square-IoU gate -> per-block segment +
// count (deterministic, no global atomics). Light rowkey plain-stored to
// rowMaxArg (overwrites stale data -> no init kernel). Zeroes K3's counter.
// (R12 verbatim.)
// ---------------------------------------------------------------------------
__global__ void __launch_bounds__(256, 1)
gate_kernel(const float* __restrict__ anc,
            const float* __restrict__ ann,
            unsigned long long* __restrict__ rowMaxArg,
            unsigned* __restrict__ seg,
            unsigned* __restrict__ segcnt,
            unsigned* __restrict__ ctr) {
    __shared__ int ss[256];
    const int tid = threadIdx.x;
    const int t = blockIdx.x * 256 + tid;   // global anchor id
    const int b = blockIdx.x >> 6;          // 64 blocks per image

    if (blockIdx.x == 0 && tid == 0) ctr[0] = 0u;  // K3 arrival counter

    const float* ab = anc + (size_t)t * 5;
    float a0 = ab[0], a1 = ab[1], a2 = ab[2], a3 = ab[3];
    float sa = 0.5f * fmaxf(a2, a3);

    unsigned passmask = 0u;
    unsigned long long rk = 0ull;
#pragma unroll
    for (int g = 0; g < G_; ++g) {
        const float* gb = ann + ((size_t)b * G_ + g) * 6;  // uniform, cached
        float v;
        if (gb[5] == -1.0f) {
            v = -1.0f;
        } else {
            float sb = 0.5f * fmaxf(gb[2], gb[3]);
            float iw = fminf(a0 + sa, gb[0] + sb) - fmaxf(a0 - sa, gb[0] - sb);
            iw = fmaxf(iw, 0.f);
            float ih = fminf(a1 + sa, gb[1] + sb) - fmaxf(a1 - sa, gb[1] - sb);
            ih = fmaxf(ih, 0.f);
            float inter = iw * ih;
            float uni = 4.f * sa * sa + 4.f * sb * sb - inter;
            float ind = inter / fmaxf(uni, 1e-8f);
            if (ind > 0.1f) passmask |= (1u << g);
            v = 0.f;  // placeholder <= any heavy IoU, same tiebreak bits
        }
        unsigned long long key =
            ((unsigned long long)enc_f32(v) << 32) | (unsigned)(G_ - 1 - g);
        if (key > rk) rk = key;
    }
    rowMaxArg[t] = rk;   // plain store; K2 atomicMaxes heavy keys on top

    // block scan -> deterministic per-block segment
    int cnt = __popc(passmask);
    ss[tid] = cnt;
    __syncthreads();
    for (int s = 1; s < 256; s <<= 1) {
        int v = (tid >= s) ? ss[tid - s] : 0;
        __syncthreads();
        ss[tid] += v;
        __syncthreads();
    }
    unsigned p = (unsigned)(ss[tid] - cnt);
    unsigned* mySeg = seg + (size_t)blockIdx.x * SEGCAP;
#pragma unroll
    for (int g = 0; g < G_; ++g) {
        if ((passmask >> g) & 1u) mySeg[p++] = ((unsigned)tid << 4) | (unsigned)g;
    }
    if (tid == 0) segcnt[blockIdx.x] = (unsigned)ss[255];
}

// ---------------------------------------------------------------------------
// K2: heavy. 256 blocks x 128 thr. Every block scans the 128 segment counts
// in LDS; grid-stride over global item index + binary search -> perfect
// balance, <=1 clip per lane. SH clip uses per-thread LDS polygon buffers
// (stride 9). Row keys: scattered global atomicMax over K1's light values.
// Col keys: LDS cells -> per-block partials. (R12 skeleton.)
// ---------------------------------------------------------------------------
__global__ void __launch_bounds__(HT_, 1)
heavy_kernel(const float* __restrict__ anc,
             const float* __restrict__ ann,
             const unsigned* __restrict__ seg,
             const unsigned* __restrict__ segcnt,
             unsigned long long* __restrict__ rowMaxArg,
             unsigned long long* __restrict__ partials) {
    __shared__ unsigned inc[NSEG];
    __shared__ unsigned long long cells[32];
    __shared__ float bufPX[HT_ * PSTR];
    __shared__ float bufPY[HT_ * PSTR];
    __shared__ float bufQX[HT_ * PSTR];
    __shared__ float bufQY[HT_ * PSTR];
    const int tid = threadIdx.x;
    float* PX = bufPX + tid * PSTR;
    float* PY = bufPY + tid * PSTR;
    float* QX = bufQX + tid * PSTR;
    float* QY = bufQY + tid * PSTR;

    if (tid < 32) cells[tid] = 0ull;
    inc[tid] = segcnt[tid];                // NSEG == blockDim.x == 128
    __syncthreads();
    for (int s = 1; s < NSEG; s <<= 1) {
        unsigned v = (tid >= s) ? inc[tid - s] : 0u;
        __syncthreads();
        inc[tid] += v;
        __syncthreads();
    }
    const unsigned n = inc[NSEG - 1];

    for (unsigned i = (unsigned)(blockIdx.x * HT_ + tid); i < n; i += HB_ * HT_) {
        // first segment s with inc[s] > i
        int lo = 0, hi = NSEG - 1;
        while (lo < hi) {
            int mid = (lo + hi) >> 1;
            if (inc[mid] > i) hi = mid; else lo = mid + 1;
        }
        unsigned base = (lo == 0) ? 0u : inc[lo - 1];
        unsigned e = seg[(size_t)lo * SEGCAP + (i - base)];
        int t2 = lo * 256 + (int)(e >> 4);
        int g = (int)(e & 15u);
        int b2 = t2 >> 14;
        const float* ab2 = anc + (size_t)t2 * 5;
        const float* gb2 = ann + ((size_t)b2 * G_ + g) * 6;
        float v = rotated_iou_pair(ab2, gb2, PX, PY, QX, QY);
        unsigned long long ev = (unsigned long long)enc_f32(v);
        atomicMax(&rowMaxArg[t2], (ev << 32) | (unsigned)(G_ - 1 - g));
        int aIdx = t2 & (A_ - 1);
        atomicMax(&cells[b2 * G_ + g], (ev << 32) | (0xFFFFFFFFu - (unsigned)aIdx));
    }
    __syncthreads();
    if (tid < 32) partials[(size_t)blockIdx.x * 32 + tid] = cells[tid];
}

// ---------------------------------------------------------------------------
// K3: colfinal + loss + final. 128 blocks x 256 thr. (R12 verbatim.)
// ---------------------------------------------------------------------------
__global__ void __launch_bounds__(256, 1)
loss_kernel(const float* __restrict__ cls_p,
            const float* __restrict__ reg_p,
            const float* __restrict__ anc,
            const float* __restrict__ ann,
            const unsigned long long* __restrict__ rowMaxArg,
            const unsigned long long* __restrict__ partials,
            float* __restrict__ pcls,
            float* __restrict__ preg,
            int* __restrict__ pnp,
            unsigned* __restrict__ ctr,
            float* __restrict__ out) {
    __shared__ unsigned long long red[256];
    __shared__ unsigned long long pk32[32];
    __shared__ float sc[256], sr[256];
    __shared__ int sp[256];
    __shared__ int lastFlag;

    const int tid = threadIdx.x;

    // ---- colfinal: reduce HB_ x 32 partials; default candidate (0.0, a=0):
    // every non-heavy entry of a valid gt column is exactly 0.0 and anchor 0
    // is the smallest index, so colmax = max(best heavy, (0.0, anchor 0)).
    {
        int cell = tid & 31, chunk = tid >> 5;   // 8 chunks x 32 heavy-blocks
        unsigned long long m = 0ull;
        for (int blk = chunk * (HB_ / 8); blk < (chunk + 1) * (HB_ / 8); ++blk) {
            unsigned long long v = partials[(size_t)blk * 32 + cell];
            if (v > m) m = v;
        }
        red[tid] = m;
    }
    __syncthreads();
    if (tid < 32) {
        unsigned long long mm =
            ((unsigned long long)enc_f32(0.0f) << 32) | 0xFFFFFFFFu;
        for (int c = 0; c < 8; ++c) {
            unsigned long long v = red[c * 32 + tid];
            if (v > mm) mm = v;
        }
        pk32[tid] = mm;
    }
    __syncthreads();

    // ---- per-anchor loss ----
    const int t = blockIdx.x * 256 + tid;
    const int b = t >> 14;
    const int a = t & (A_ - 1);

    unsigned long long rk = rowMaxArg[t];
    unsigned ehi = (unsigned)(rk >> 32);
    int arg = (G_ - 1) - (int)(rk & 0xFu);

    bool forcedf = false;
#pragma unroll
    for (int g = 0; g < G_; ++g) {
        unsigned long long pkv = pk32[b * G_ + g];
        float lab = ann[((size_t)b * G_ + g) * 6 + 5];
        unsigned hi = (unsigned)(pkv >> 32);
        unsigned ai = 0xFFFFFFFFu - (unsigned)pkv;
        forcedf |= (lab != -1.0f) && (hi < ENC_HALF) && (ai == (unsigned)a);
    }

    bool pos = (ehi >= ENC_HALF) || forcedf;
    const float* g6 = ann + ((size_t)b * G_ + arg) * 6;
    int cls = (int)g6[5];

    float csum = 0.f;
    if (pos || ehi < ENC_04) {
        const float* pr = cls_p + (size_t)t * C_;
#pragma unroll
        for (int c = 0; c < C_; ++c) {
            float tgt = (pos && c == cls) ? 1.f : 0.f;
            float pv = fminf(fmaxf(pr[c], 1e-4f), 1.f - 1e-4f);
            float af = (tgt == 1.f) ? 0.25f : 0.75f;
            float x = (tgt == 1.f) ? (1.f - pv) : pv;
            float fw = af * x * x;
            float bce = -(tgt * logf(pv + 1e-6f) + (1.f - tgt) * logf(1.f - pv + 1e-6f));
            csum += fw * bce;
        }
    }

    float rsum = 0.f;
    if (pos) {
        const float* ex = anc + (size_t)t * 5;
        const float* rp = reg_p + (size_t)t * 5;
        float ew = fmaxf(ex[2], 1.f), eh2 = fmaxf(ex[3], 1.f);
        float gw = fmaxf(g6[2], 1.f), gh = fmaxf(g6[3], 1.f);
        float tg[5];
        tg[0] = 10.f * (g6[0] - ex[0]) / ew;
        tg[1] = 10.f * (g6[1] - ex[1]) / eh2;
        tg[2] = 10.f * logf(gw / ew);
        tg[3] = 5.f * logf(gh / eh2);
        tg[4] = 15.f * (tanf(g6[4] * D2Rf) - tanf(ex[4] * D2Rf));
        const float BETAf = (float)(1.0 / 9.0);
#pragma unroll
        for (int i = 0; i < 5; ++i) {
            float d = fabsf(rp[i] - tg[i]);
            rsum += (d < BETAf) ? 0.5f * d * d / BETAf : d - 0.5f * BETAf;
        }
    }

    sc[tid] = csum; sr[tid] = rsum; sp[tid] = pos ? 1 : 0;
    __syncthreads();
    for (int s = 128; s > 0; s >>= 1) {
        if (tid < s) {
            sc[tid] += sc[tid + s];
            sr[tid] += sr[tid + s];
            sp[tid] += sp[tid + s];
        }
        __syncthreads();
    }
    if (tid == 0) {
        pcls[blockIdx.x] = sc[0];
        preg[blockIdx.x] = sr[0];
        pnp[blockIdx.x] = sp[0];
        __threadfence();   // release partials (writeback to coherent point)
        unsigned v = atomicAdd(ctr, 1u);   // single RMW, no spinning
        lastFlag = (v == (unsigned)(LB_ - 1));
    }
    __syncthreads();

    // ---- last-arriving block: deterministic ordered final combine ----
    if (lastFlag) {
        __threadfence();   // acquire (invalidate local caches)
        if (tid < LB_) {
            sc[tid] = pcls[tid];
            sr[tid] = preg[tid];
            sp[tid] = pnp[tid];
        }
        __syncthreads();
        if (tid == 0) {
            const int BPI = LB_ / B_;   // 64 blocks per image
            float cm = 0.f, rm = 0.f;
            for (int bb = 0; bb < B_; ++bb) {
                float cs = 0.f, rs = 0.f; int np = 0;
                for (int i = 0; i < BPI; ++i) {
                    cs += sc[bb * BPI + i];
                    rs += sr[bb * BPI + i];
                    np += sp[bb * BPI + i];
                }
                bool has = false;
                for (int g = 0; g < G_; ++g)
                    if (ann[((size_t)bb * G_ + g) * 6 + 5] != -1.0f) has = true;
                float c_ = cs / fmaxf((float)np, 1.f);
                int d5 = np * 5; if (d5 < 1) d5 = 1;
                float r_ = (np > 0) ? rs / (float)d5 : 0.f;
                cm += has ? c_ : 0.f;
                rm += has ? r_ : 0.f;
            }
            out[0] = cm / (float)B_;
            out[1] = rm / (float)B_;
        }
    }
}

// ---------------------------------------------------------------------------
extern "C" void kernel_launch(void* const* d_in, const int* in_sizes, int n_in,
                              void* d_out, int out_size, void* d_ws, size_t ws_size,
                              hipStream_t stream) {
    const float* cls_p = (const float*)d_in[0];   // (B,A,C)
    const float* reg_p = (const float*)d_in[1];   // (B,A,5)
    const float* anc   = (const float*)d_in[2];   // (B,A,5)
    const float* ann   = (const float*)d_in[3];   // (B,G,6)
    float* out = (float*)d_out;

    // workspace (every word consumed is rewritten each call; no memset)
    char* ws = (char*)d_ws;
    unsigned* ctrp = (unsigned*)ws;                                   // 256 B
    unsigned long long* rowMaxArg = (unsigned long long*)(ws + 256);  // 256 KB
    unsigned long long* partials = rowMaxArg + (size_t)B_ * A_;       // HB_*32*8 = 64 KB
    unsigned* segcnt = (unsigned*)(partials + (size_t)HB_ * 32);      // NSEG u32
    unsigned* seg    = segcnt + NSEG;                                 // NSEG*SEGCAP*4 = 2 MB
    float* pcls = (float*)(seg + (size_t)NSEG * SEGCAP);              // LB_
    float* preg = pcls + LB_;
    int*   pnp  = (int*)(preg + LB_);

    gate_kernel<<<NSEG, 256, 0, stream>>>(anc, ann, rowMaxArg, seg, segcnt, ctrp);
    heavy_kernel<<<HB_, HT_, 0, stream>>>(anc, ann, seg, segcnt, rowMaxArg, partials);
    loss_kernel<<<LB_, 256, 0, stream>>>(cls_p, reg_p, anc, ann, rowMaxArg,
                                         partials, pcls, preg, pnp, ctrp, out);
}

// Round 17
// 31.747 us; speedup vs baseline: 1.5625x; 1.0102x over previous
//
#include <hip/hip_runtime.h>

#define B_ 2
#define A_ 16384
#define C_ 15
#define G_ 16
#define D2Rf 0.017453292519943295f
#define ENC_HALF 0xBF000000u   // enc(0.5f)
#define ENC_04   0xBECCCCCDu   // enc(0.4f)
#define NSEG 128               // gate blocks / segments
#define HB_ 256                // heavy blocks
#define HT_ 256                // heavy threads per block (2x TLP vs R16)
#define LB_ 128                // loss blocks
#define SEGCAP 4096            // per-segment worklist capacity (256*16 max)
#define PSTR 9                 // LDS polygon-buffer stride (2-way bank alias = free)

__device__ __forceinline__ unsigned enc_f32(float f) {
    unsigned u = __float_as_uint(f);
    return u ^ ((u >> 31) ? 0xFFFFFFFFu : 0x80000000u);
}

// ---------------------------------------------------------------------------
// Rotated IoU via Sutherland-Hodgman (R16, verified absmax 0.0): clip rect A
// against rect G's 4 half-planes; vertices emerge in boundary order ->
// shoelace directly. Polygon buffers are per-thread LDS slices.
// ---------------------------------------------------------------------------
__device__ __forceinline__ void rect_corners4(const float* b, float X[4], float Y[4]) {
    float th = b[4] * D2Rf;
    float c = cosf(th), s = sinf(th);
    const float SX[4] = {-1.f, 1.f, 1.f, -1.f};
    const float SY[4] = {-1.f, -1.f, 1.f, 1.f};
    float hw = 0.5f * b[2], hh = 0.5f * b[3];
#pragma unroll
    for (int i = 0; i < 4; ++i) {
        float dx = hw * SX[i];
        float dy = hh * SY[i];
        X[i] = b[0] + dx * c - dy * s;
        Y[i] = b[1] + dx * s + dy * c;
    }
}

__device__ __forceinline__ float rotated_iou_pair(const float* ab, const float* gb,
                                                  float* PX, float* PY,
                                                  float* QX, float* QY) {
    float ax[4], ay[4], gx[4], gy[4];
    rect_corners4(ab, ax, ay);
    rect_corners4(gb, gx, gy);

#pragma unroll
    for (int i = 0; i < 4; ++i) { PX[i] = ax[i]; PY[i] = ay[i]; }
    int n = 4;

    float* px = PX; float* py = PY;
    float* qx = QX; float* qy = QY;

#pragma unroll
    for (int j = 0; j < 4; ++j) {
        float e0x = gx[j], e0y = gy[j];
        float ex = gx[(j + 1) & 3] - e0x;
        float ey = gy[(j + 1) & 3] - e0y;
        int m = 0;
        float sxv = px[n - 1], syv = py[n - 1];
        float ss = ex * (syv - e0y) - ey * (sxv - e0x);   // >=0 = inside (CCW)
        for (int i = 0; i < n; ++i) {
            float exv = px[i], eyv = py[i];
            float se = ex * (eyv - e0y) - ey * (exv - e0x);
            if ((ss >= 0.f) != (se >= 0.f)) {
                float tpar = ss / (ss - se);
                qx[m] = sxv + tpar * (exv - sxv);
                qy[m] = syv + tpar * (eyv - syv);
                ++m;
            }
            if (se >= 0.f) { qx[m] = exv; qy[m] = eyv; ++m; }
            sxv = exv; syv = eyv; ss = se;
        }
        n = m;
        // swap P <-> Q
        float* tx = px; px = qx; qx = tx;
        float* ty = py; py = qy; qy = ty;
        if (n == 0) break;
    }

    float inter = 0.f;
    if (n >= 3) {
        float x0 = px[0], y0 = py[0];
        float xp = x0, yp = y0, ssum = 0.f;
        for (int r = 1; r < n; ++r) {
            float xc = px[r], yc = py[r];
            ssum += xp * yc - yp * xc;
            xp = xc; yp = yc;
        }
        ssum += xp * y0 - yp * x0;
        inter = 0.5f * fabsf(ssum);
    }
    float uni = ab[2] * ab[3] + gb[2] * gb[3] - inter;
    return inter / fmaxf(uni, 1e-8f);
}

// ---------------------------------------------------------------------------
// K1: gate. 128 blocks x 256 thr. Square-IoU gate -> per-block u16 segment +
// count (deterministic, no global atomics). Light rowkey plain-stored to
// rowMaxArg (overwrites stale data -> no init kernel). Zeroes K3's counter.
// ---------------------------------------------------------------------------
__global__ void __launch_bounds__(256, 1)
gate_kernel(const float* __restrict__ anc,
            const float* __restrict__ ann,
            unsigned long long* __restrict__ rowMaxArg,
            unsigned short* __restrict__ seg,
            unsigned* __restrict__ segcnt,
            unsigned* __restrict__ ctr) {
    __shared__ int ss[256];
    const int tid = threadIdx.x;
    const int t = blockIdx.x * 256 + tid;   // global anchor id
    const int b = blockIdx.x >> 6;          // 64 blocks per image

    if (blockIdx.x == 0 && tid == 0) ctr[0] = 0u;  // K3 arrival counter

    const float* ab = anc + (size_t)t * 5;
    float a0 = ab[0], a1 = ab[1], a2 = ab[2], a3 = ab[3];
    float sa = 0.5f * fmaxf(a2, a3);

    unsigned passmask = 0u;
    unsigned long long rk = 0ull;
#pragma unroll
    for (int g = 0; g < G_; ++g) {
        const float* gb = ann + ((size_t)b * G_ + g) * 6;  // uniform, cached
        float v;
        if (gb[5] == -1.0f) {
            v = -1.0f;
        } else {
            float sb = 0.5f * fmaxf(gb[2], gb[3]);
            float iw = fminf(a0 + sa, gb[0] + sb) - fmaxf(a0 - sa, gb[0] - sb);
            iw = fmaxf(iw, 0.f);
            float ih = fminf(a1 + sa, gb[1] + sb) - fmaxf(a1 - sa, gb[1] - sb);
            ih = fmaxf(ih, 0.f);
            float inter = iw * ih;
            float uni = 4.f * sa * sa + 4.f * sb * sb - inter;
            float ind = inter / fmaxf(uni, 1e-8f);
            if (ind > 0.1f) passmask |= (1u << g);
            v = 0.f;  // placeholder <= any heavy IoU, same tiebreak bits
        }
        unsigned long long key =
            ((unsigned long long)enc_f32(v) << 32) | (unsigned)(G_ - 1 - g);
        if (key > rk) rk = key;
    }
    rowMaxArg[t] = rk;   // plain store; K2 atomicMaxes heavy keys on top

    // block scan -> deterministic per-block segment
    int cnt = __popc(passmask);
    ss[tid] = cnt;
    __syncthreads();
    for (int s = 1; s < 256; s <<= 1) {
        int v = (tid >= s) ? ss[tid - s] : 0;
        __syncthreads();
        ss[tid] += v;
        __syncthreads();
    }
    unsigned p = (unsigned)(ss[tid] - cnt);
    unsigned short* mySeg = seg + (size_t)blockIdx.x * SEGCAP;
#pragma unroll
    for (int g = 0; g < G_; ++g) {
        if ((passmask >> g) & 1u)
            mySeg[p++] = (unsigned short)(((unsigned)tid << 4) | (unsigned)g);
    }
    if (tid == 0) segcnt[blockIdx.x] = (unsigned)ss[255];
}

// ---------------------------------------------------------------------------
// K2: heavy. 256 blocks x 256 thr (2x TLP to hide the SH clip's LDS-chain
// latency; <=1 clip per lane still). Every block scans the 128 segment
// counts in LDS; grid-stride over global item index + binary search ->
// perfect balance. Row keys: scattered global atomicMax over K1's light
// values. Col keys: LDS cells -> per-block partials.
// ---------------------------------------------------------------------------
__global__ void __launch_bounds__(HT_, 1)
heavy_kernel(const float* __restrict__ anc,
             const float* __restrict__ ann,
             const unsigned short* __restrict__ seg,
             const unsigned* __restrict__ segcnt,
             unsigned long long* __restrict__ rowMaxArg,
             unsigned long long* __restrict__ partials) {
    __shared__ unsigned inc[NSEG];
    __shared__ unsigned long long cells[32];
    __shared__ float bufPX[HT_ * PSTR];
    __shared__ float bufPY[HT_ * PSTR];
    __shared__ float bufQX[HT_ * PSTR];
    __shared__ float bufQY[HT_ * PSTR];
    const int tid = threadIdx.x;
    float* PX = bufPX + tid * PSTR;
    float* PY = bufPY + tid * PSTR;
    float* QX = bufQX + tid * PSTR;
    float* QY = bufQY + tid * PSTR;

    if (tid < 32) cells[tid] = 0ull;
    if (tid < NSEG) inc[tid] = segcnt[tid];
    __syncthreads();
    for (int s = 1; s < NSEG; s <<= 1) {
        unsigned v = (tid < NSEG && tid >= s) ? inc[tid - s] : 0u;
        __syncthreads();
        if (tid < NSEG) inc[tid] += v;
        __syncthreads();
    }
    const unsigned n = inc[NSEG - 1];

    for (unsigned i = (unsigned)(blockIdx.x * HT_ + tid); i < n; i += HB_ * HT_) {
        // first segment s with inc[s] > i
        int lo = 0, hi = NSEG - 1;
        while (lo < hi) {
            int mid = (lo + hi) >> 1;
            if (inc[mid] > i) hi = mid; else lo = mid + 1;
        }
        unsigned base = (lo == 0) ? 0u : inc[lo - 1];
        unsigned e = (unsigned)seg[(size_t)lo * SEGCAP + (i - base)];
        int t2 = lo * 256 + (int)(e >> 4);
        int g = (int)(e & 15u);
        int b2 = t2 >> 14;
        const float* ab2 = anc + (size_t)t2 * 5;
        const float* gb2 = ann + ((size_t)b2 * G_ + g) * 6;
        float v = rotated_iou_pair(ab2, gb2, PX, PY, QX, QY);
        unsigned long long ev = (unsigned long long)enc_f32(v);
        atomicMax(&rowMaxArg[t2], (ev << 32) | (unsigned)(G_ - 1 - g));
        int aIdx = t2 & (A_ - 1);
        atomicMax(&cells[b2 * G_ + g], (ev << 32) | (0xFFFFFFFFu - (unsigned)aIdx));
    }
    __syncthreads();
    if (tid < 32) partials[(size_t)blockIdx.x * 32 + tid] = cells[tid];
}

// ---------------------------------------------------------------------------
// K3: colfinal + loss + final. 128 blocks x 256 thr. (R12/R16 verbatim.)
// ---------------------------------------------------------------------------
__global__ void __launch_bounds__(256, 1)
loss_kernel(const float* __restrict__ cls_p,
            const float* __restrict__ reg_p,
            const float* __restrict__ anc,
            const float* __restrict__ ann,
            const unsigned long long* __restrict__ rowMaxArg,
            const unsigned long long* __restrict__ partials,
            float* __restrict__ pcls,
            float* __restrict__ preg,
            int* __restrict__ pnp,
            unsigned* __restrict__ ctr,
            float* __restrict__ out) {
    __shared__ unsigned long long red[256];
    __shared__ unsigned long long pk32[32];
    __shared__ float sc[256], sr[256];
    __shared__ int sp[256];
    __shared__ int lastFlag;

    const int tid = threadIdx.x;

    // ---- colfinal: reduce HB_ x 32 partials; default candidate (0.0, a=0):
    // every non-heavy entry of a valid gt column is exactly 0.0 and anchor 0
    // is the smallest index, so colmax = max(best heavy, (0.0, anchor 0)).
    {
        int cell = tid & 31, chunk = tid >> 5;   // 8 chunks x 32 heavy-blocks
        unsigned long long m = 0ull;
        for (int blk = chunk * (HB_ / 8); blk < (chunk + 1) * (HB_ / 8); ++blk) {
            unsigned long long v = partials[(size_t)blk * 32 + cell];
            if (v > m) m = v;
        }
        red[tid] = m;
    }
    __syncthreads();
    if (tid < 32) {
        unsigned long long mm =
            ((unsigned long long)enc_f32(0.0f) << 32) | 0xFFFFFFFFu;
        for (int c = 0; c < 8; ++c) {
            unsigned long long v = red[c * 32 + tid];
            if (v > mm) mm = v;
        }
        pk32[tid] = mm;
    }
    __syncthreads();

    // ---- per-anchor loss ----
    const int t = blockIdx.x * 256 + tid;
    const int b = t >> 14;
    const int a = t & (A_ - 1);

    unsigned long long rk = rowMaxArg[t];
    unsigned ehi = (unsigned)(rk >> 32);
    int arg = (G_ - 1) - (int)(rk & 0xFu);

    bool forcedf = false;
#pragma unroll
    for (int g = 0; g < G_; ++g) {
        unsigned long long pkv = pk32[b * G_ + g];
        float lab = ann[((size_t)b * G_ + g) * 6 + 5];
        unsigned hi = (unsigned)(pkv >> 32);
        unsigned ai = 0xFFFFFFFFu - (unsigned)pkv;
        forcedf |= (lab != -1.0f) && (hi < ENC_HALF) && (ai == (unsigned)a);
    }

    bool pos = (ehi >= ENC_HALF) || forcedf;
    const float* g6 = ann + ((size_t)b * G_ + arg) * 6;
    int cls = (int)g6[5];

    float csum = 0.f;
    if (pos || ehi < ENC_04) {
        const float* pr = cls_p + (size_t)t * C_;
#pragma unroll
        for (int c = 0; c < C_; ++c) {
            float tgt = (pos && c == cls) ? 1.f : 0.f;
            float pv = fminf(fmaxf(pr[c], 1e-4f), 1.f - 1e-4f);
            float af = (tgt == 1.f) ? 0.25f : 0.75f;
            float x = (tgt == 1.f) ? (1.f - pv) : pv;
            float fw = af * x * x;
            float bce = -(tgt * logf(pv + 1e-6f) + (1.f - tgt) * logf(1.f - pv + 1e-6f));
            csum += fw * bce;
        }
    }

    float rsum = 0.f;
    if (pos) {
        const float* ex = anc + (size_t)t * 5;
        const float* rp = reg_p + (size_t)t * 5;
        float ew = fmaxf(ex[2], 1.f), eh2 = fmaxf(ex[3], 1.f);
        float gw = fmaxf(g6[2], 1.f), gh = fmaxf(g6[3], 1.f);
        float tg[5];
        tg[0] = 10.f * (g6[0] - ex[0]) / ew;
        tg[1] = 10.f * (g6[1] - ex[1]) / eh2;
        tg[2] = 10.f * logf(gw / ew);
        tg[3] = 5.f * logf(gh / eh2);
        tg[4] = 15.f * (tanf(g6[4] * D2Rf) - tanf(ex[4] * D2Rf));
        const float BETAf = (float)(1.0 / 9.0);
#pragma unroll
        for (int i = 0; i < 5; ++i) {
            float d = fabsf(rp[i] - tg[i]);
            rsum += (d < BETAf) ? 0.5f * d * d / BETAf : d - 0.5f * BETAf;
        }
    }

    sc[tid] = csum; sr[tid] = rsum; sp[tid] = pos ? 1 : 0;
    __syncthreads();
    for (int s = 128; s > 0; s >>= 1) {
        if (tid < s) {
            sc[tid] += sc[tid + s];
            sr[tid] += sr[tid + s];
            sp[tid] += sp[tid + s];
        }
        __syncthreads();
    }
    if (tid == 0) {
        pcls[blockIdx.x] = sc[0];
        preg[blockIdx.x] = sr[0];
        pnp[blockIdx.x] = sp[0];
        __threadfence();   // release partials (writeback to coherent point)
        unsigned v = atomicAdd(ctr, 1u);   // single RMW, no spinning
        lastFlag = (v == (unsigned)(LB_ - 1));
    }
    __syncthreads();

    // ---- last-arriving block: deterministic ordered final combine ----
    if (lastFlag) {
        __threadfence();   // acquire (invalidate local caches)
        if (tid < LB_) {
            sc[tid] = pcls[tid];
            sr[tid] = preg[tid];
            sp[tid] = pnp[tid];
        }
        __syncthreads();
        if (tid == 0) {
            const int BPI = LB_ / B_;   // 64 blocks per image
            float cm = 0.f, rm = 0.f;
            for (int bb = 0; bb < B_; ++bb) {
                float cs = 0.f, rs = 0.f; int np = 0;
                for (int i = 0; i < BPI; ++i) {
                    cs += sc[bb * BPI + i];
                    rs += sr[bb * BPI + i];
                    np += sp[bb * BPI + i];
                }
                bool has = false;
                for (int g = 0; g < G_; ++g)
                    if (ann[((size_t)bb * G_ + g) * 6 + 5] != -1.0f) has = true;
                float c_ = cs / fmaxf((float)np, 1.f);
                int d5 = np * 5; if (d5 < 1) d5 = 1;
                float r_ = (np > 0) ? rs / (float)d5 : 0.f;
                cm += has ? c_ : 0.f;
                rm += has ? r_ : 0.f;
            }
            out[0] = cm / (float)B_;
            out[1] = rm / (float)B_;
        }
    }
}

// ---------------------------------------------------------------------------
extern "C" void kernel_launch(void* const* d_in, const int* in_sizes, int n_in,
                              void* d_out, int out_size, void* d_ws, size_t ws_size,
                              hipStream_t stream) {
    const float* cls_p = (const float*)d_in[0];   // (B,A,C)
    const float* reg_p = (const float*)d_in[1];   // (B,A,5)
    const float* anc   = (const float*)d_in[2];   // (B,A,5)
    const float* ann   = (const float*)d_in[3];   // (B,G,6)
    float* out = (float*)d_out;

    // workspace (every word consumed is rewritten each call; no memset)
    char* ws = (char*)d_ws;
    unsigned* ctrp = (unsigned*)ws;                                   // 256 B
    unsigned long long* rowMaxArg = (unsigned long long*)(ws + 256);  // 256 KB
    unsigned long long* partials = rowMaxArg + (size_t)B_ * A_;       // HB_*32*8 = 64 KB
    unsigned* segcnt = (unsigned*)(partials + (size_t)HB_ * 32);      // NSEG u32
    unsigned short* seg = (unsigned short*)(segcnt + NSEG);           // NSEG*SEGCAP*2 = 1 MB
    float* pcls = (float*)(seg + (size_t)NSEG * SEGCAP);              // LB_
    float* preg = pcls + LB_;
    int*   pnp  = (int*)(preg + LB_);

    gate_kernel<<<NSEG, 256, 0, stream>>>(anc, ann, rowMaxArg, seg, segcnt, ctrp);
    heavy_kernel<<<HB_, HT_, 0, stream>>>(anc, ann, seg, segcnt, rowMaxArg, partials);
    loss_kernel<<<LB_, 256, 0, stream>>>(cls_p, reg_p, anc, ann, rowMaxArg,
                                         partials, pcls, preg, pnp, ctrp, out);
}